// Round 6
// baseline (299.193 us; speedup 1.0000x reference)
//
#include <hip/hip_runtime.h>
#include <hip/hip_bf16.h>
#include <math.h>

// Problem constants
#define B_    32
#define IC    512
#define OC    256
#define HW    32
#define OHW   64

// ws layout:
//   xcl  at offset 0:          bf16 [32][34][34][512]  = 37,879,808 B (zero-padded channels-last)
//   Amat at offset 37,879,808: bf16 [1024][4608]       =  9,437,184 B
#define WS_AMAT_OFF 37879808ull

typedef __attribute__((ext_vector_type(8))) short short8;
typedef __attribute__((ext_vector_type(4))) float f32x4;
typedef __attribute__((ext_vector_type(2))) float f32x2;

#define GPTR(x) ((const __attribute__((address_space(1))) char*)(x))
#define LPTR(x) ((__attribute__((address_space(3))) char*)(x))

// ---------------------------------------------------------------------------
// Weight transform. M-row order (oc*4 + p): 4 consecutive C-rows per lane are
// the 4 parities of one oc -> coalesced 2x2 output quads in the epilogue.
__global__ __launch_bounds__(256) void wtrans(const float* __restrict__ w,
                                              __hip_bfloat16* __restrict__ Amat) {
    int t = blockIdx.x * blockDim.x + threadIdx.x;  // 131072 threads
    int ic = t & 511, oc = t >> 9;

    const float gain = 1.0f / sqrtf((float)(IC * 9));
    float wl[3][3];
    const float* wp = w + ((size_t)oc * IC + ic) * 9;
#pragma unroll
    for (int i = 0; i < 3; ++i)
#pragma unroll
        for (int j = 0; j < 3; ++j) wl[i][j] = wp[i * 3 + j] * gain;

    const float f1[4] = {1.f, 3.f, 3.f, 1.f};
    float g2[6][6];
#pragma unroll
    for (int s = 0; s < 6; ++s)
#pragma unroll
        for (int tt = 0; tt < 6; ++tt) {
            float acc = 0.f;
#pragma unroll
            for (int i = 0; i < 3; ++i)
#pragma unroll
                for (int j = 0; j < 3; ++j) {
                    int a = s - 2 + i, b = tt - 2 + j;
                    if (a >= 0 && a < 4 && b >= 0 && b < 4)
                        acc += wl[i][j] * f1[a] * f1[b] * 0.0625f;
                }
            g2[s][tt] = acc;
        }

#pragma unroll
    for (int pm = 0; pm < 2; ++pm)
#pragma unroll
        for (int pn = 0; pn < 2; ++pn)
#pragma unroll
            for (int k = 0; k < 3; ++k)
#pragma unroll
                for (int l = 0; l < 3; ++l) {
                    int p = pm * 2 + pn;
                    size_t idx = ((size_t)(oc * 4 + p) * 4608) + (k * 3 + l) * 512 + ic;
                    Amat[idx] = __float2bfloat16(g2[2 * k + 1 - pm][2 * l + 1 - pn]);
                }
}

// ---------------------------------------------------------------------------
// x (fp32 NCHW) -> xcl (bf16, [b][34][34][512], zero halo), via LDS transpose.
__global__ __launch_bounds__(256) void xprep(const float* __restrict__ x,
                                             __hip_bfloat16* __restrict__ xcl) {
    int blk = blockIdx.x;            // 32*34 blocks
    int b = blk / 34, h = blk % 34;
    __hip_bfloat16* orow = xcl + (size_t)(b * 34 + h) * 34 * 512;
    int t = threadIdx.x;
    bool hin = (h >= 1 && h <= 32);

    for (int i = t; i < 2 * 512; i += 256) {
        int wsel = i >> 9, ic = i & 511;
        orow[(size_t)(wsel * 33) * 512 + ic] = __float2bfloat16(0.f);
    }

    __shared__ float ls[16][33];
    int icl_r = t >> 5, wv_r = t & 31;
    int wv_w = t >> 3, icl_w = t & 7;

    for (int ic0 = 0; ic0 < 512; ic0 += 16) {
        __syncthreads();
#pragma unroll
        for (int pp = 0; pp < 2; ++pp) {
            int icll = icl_r + pp * 8;
            float v = 0.f;
            if (hin) v = x[(((size_t)b * IC + ic0 + icll) * HW + (h - 1)) * HW + wv_r];
            ls[icll][wv_r] = v;
        }
        __syncthreads();
#pragma unroll
        for (int pp = 0; pp < 2; ++pp) {
            int icll = icl_w + pp * 8;
            orow[(size_t)(wv_w + 1) * 512 + ic0 + icll] = __float2bfloat16(ls[icll][wv_w]);
        }
    }
}

// ---------------------------------------------------------------------------
// Implicit-GEMM, 256x256 tile, BK=64, 8 waves (2Mx4N), 2 LDS buffers (dbuf),
// 8-phase-style schedule (4 phases per K-tile of 64), T2 granule swizzle,
// T5 setprio, boundary vmcnt on 3-phase-old loads.
//
// LDS per buffer: A[256][64]bf16 = 32 KB, B[256][64] at +32768. 2 bufs = 128 KB.
// Swizzle: row r (128 B = 8 granules of 16 B): granule g stored at slot
// g ^ (r&7); both sides (pre-swizzled global source + swizzled ds_read).
__global__ __launch_bounds__(512, 2) void gemm_conv(const __hip_bfloat16* __restrict__ Amat,
                                                    const __hip_bfloat16* __restrict__ xcl,
                                                    const float* __restrict__ bias,
                                                    float* __restrict__ out) {
    __shared__ __align__(1024) char lds[2 * 65536];

    const int NT = 72;               // K-tiles of 64 (K = 4608)
    int bid = blockIdx.x;
    int mt = bid & 3;                // XCD x gets mt = x&3 -> A-panel L2-resident
    int nt = bid >> 2;               // 0..127
    int tid = threadIdx.x;
    int wid = tid >> 6;
    int lane = tid & 63;
    int wr = wid >> 2;               // 0..1  (M half: rows wr*128..+127)
    int wc = wid & 3;                // 0..3  (N quarter: cols wc*64..+63)
    int q = lane >> 4;               // k-granule within MFMA K=32
    int lr = lane & 15;

    // ---- staging thread constants (swizzle folded into global source) ----
    int r_ = tid >> 3;               // local row within a 64-row chunk
    int s_ = tid & 7;                // LDS slot
    int g_ = s_ ^ (r_ & 7);          // global granule fetched into slot s_

    const char* GA = (const char*)Amat;
    const char* GB = (const char*)xcl;

    int asrc[4], bsrc[4], dstL[4];   // index i = h*2 + q2  (h: 128-row half, q2: 64-row quarter)
#pragma unroll
    for (int h = 0; h < 2; ++h)
#pragma unroll
        for (int q2 = 0; q2 < 2; ++q2) {
            int i = h * 2 + q2;
            int rr = h * 128 + q2 * 64 + r_;               // 0..255 tile-local row
            asrc[i] = (mt * 256 + rr) * 9216 + g_ * 16;     // Amat row pitch 9216 B
            int n = nt * 256 + rr;
            int bb = n >> 10, uu = (n >> 5) & 31, vv = n & 31;
            bsrc[i] = (((bb * 34 + uu) * 34) + vv) * 1024 + g_ * 16;
            dstL[i] = h * 16384 + q2 * 8192 + wid * 1024;   // + lane*16 by HW
        }

    // ---- ds_read bases (kh = K-half of the 64-wide tile) ----
    int swz0 = ((q ^ (lr & 7)) << 4);          // kh0: granule q
    int swz1 = (((4 + q) ^ (lr & 7)) << 4);    // kh1: granule 4+q
    int ArdB = (wr * 128 + lr) * 128;
    int BrdB = 32768 + (wc * 64 + lr) * 128;
    int Ard0b = ArdB + swz0, Ard1b = ArdB + swz1;
    int Brd0b = BrdB + swz0, Brd1b = BrdB + swz1;

    f32x4 acc[8][4];
#pragma unroll
    for (int mi = 0; mi < 8; ++mi)
#pragma unroll
        for (int ni = 0; ni < 4; ++ni) acc[mi][ni] = (f32x4){0.f, 0.f, 0.f, 0.f};

    auto STAGE_A = [&](int T1) {     // 4 global_load_lds: full A tile of T1
        int nb = (T1 & 1) << 16;
        int ao = T1 * 128;
#pragma unroll
        for (int i = 0; i < 4; ++i)
            __builtin_amdgcn_global_load_lds(GPTR(GA + asrc[i] + ao),
                                             LPTR(lds + nb + dstL[i]), 16, 0, 0);
    };
    auto STAGE_B = [&](int T1) {     // 4 global_load_lds: full B tile of T1
        int kl = T1 >> 3;
        int kh = (kl * 11) >> 5;     // kl/3 for kl in [0,9)
        int kw = kl - 3 * kh;
        int bo = (kh * 34 + kw) * 1024 + (T1 & 7) * 128;
        int nb = (T1 & 1) << 16;
#pragma unroll
        for (int i = 0; i < 4; ++i)
            __builtin_amdgcn_global_load_lds(GPTR(GB + bsrc[i] + bo),
                                             LPTR(lds + nb + 32768 + dstL[i]), 16, 0, 0);
    };

#define LGKM0_FENCE() do { asm volatile("s_waitcnt lgkmcnt(0)" ::: "memory"); \
                           __builtin_amdgcn_sched_barrier(0); } while (0)

    // prologue: stage tile 0, wait, barrier
    STAGE_A(0);
    STAGE_B(0);
    asm volatile("s_waitcnt vmcnt(0)" ::: "memory");
    __builtin_amdgcn_s_barrier();

#pragma unroll 2
    for (int T = 0; T < NT; ++T) {
        int buf = (T & 1) << 16;
        int Ard0 = Ard0b + buf, Ard1 = Ard1b + buf;
        int Brd0 = Brd0b + buf, Brd1 = Brd1b + buf;
        short8 bF0[4], bF1[4], aP0[4], aP1[4], aP2[4], aP3[4];

        // ---- phase 0: stage A(T+1); read B.kh0 + A.mh0.kh0; MFMA mh0/kh0 ----
        if (T + 1 < NT) STAGE_A(T + 1);
#pragma unroll
        for (int ni = 0; ni < 4; ++ni) bF0[ni] = *(const short8*)(lds + Brd0 + ni * 2048);
#pragma unroll
        for (int mi = 0; mi < 4; ++mi) aP0[mi] = *(const short8*)(lds + Ard0 + mi * 2048);
        __builtin_amdgcn_s_barrier();
        LGKM0_FENCE();
        __builtin_amdgcn_s_setprio(1);
#pragma unroll
        for (int mi = 0; mi < 4; ++mi)
#pragma unroll
            for (int ni = 0; ni < 4; ++ni)
                acc[mi][ni] = __builtin_amdgcn_mfma_f32_16x16x32_bf16(
                    aP0[mi], bF0[ni], acc[mi][ni], 0, 0, 0);
        __builtin_amdgcn_s_setprio(0);
        __builtin_amdgcn_s_barrier();

        // ---- phase 1: stage B(T+1); read A.mh1.kh0; MFMA mh1/kh0 ----
        if (T + 1 < NT) STAGE_B(T + 1);
#pragma unroll
        for (int mi = 0; mi < 4; ++mi)
            aP1[mi] = *(const short8*)(lds + Ard0 + 8192 + mi * 2048);
        __builtin_amdgcn_s_barrier();
        LGKM0_FENCE();
        __builtin_amdgcn_s_setprio(1);
#pragma unroll
        for (int mi = 0; mi < 4; ++mi)
#pragma unroll
            for (int ni = 0; ni < 4; ++ni)
                acc[4 + mi][ni] = __builtin_amdgcn_mfma_f32_16x16x32_bf16(
                    aP1[mi], bF0[ni], acc[4 + mi][ni], 0, 0, 0);
        __builtin_amdgcn_s_setprio(0);
        __builtin_amdgcn_s_barrier();

        // ---- phase 2: read B.kh1 + A.mh0.kh1; MFMA mh0/kh1 ----
#pragma unroll
        for (int ni = 0; ni < 4; ++ni) bF1[ni] = *(const short8*)(lds + Brd1 + ni * 2048);
#pragma unroll
        for (int mi = 0; mi < 4; ++mi) aP2[mi] = *(const short8*)(lds + Ard1 + mi * 2048);
        __builtin_amdgcn_s_barrier();
        LGKM0_FENCE();
        __builtin_amdgcn_s_setprio(1);
#pragma unroll
        for (int mi = 0; mi < 4; ++mi)
#pragma unroll
            for (int ni = 0; ni < 4; ++ni)
                acc[mi][ni] = __builtin_amdgcn_mfma_f32_16x16x32_bf16(
                    aP2[mi], bF1[ni], acc[mi][ni], 0, 0, 0);
        __builtin_amdgcn_s_setprio(0);
        __builtin_amdgcn_s_barrier();

        // ---- phase 3: read A.mh1.kh1; MFMA mh1/kh1; boundary drain ----
#pragma unroll
        for (int mi = 0; mi < 4; ++mi)
            aP3[mi] = *(const short8*)(lds + Ard1 + 8192 + mi * 2048);
        __builtin_amdgcn_s_barrier();
        LGKM0_FENCE();
        __builtin_amdgcn_s_setprio(1);
#pragma unroll
        for (int mi = 0; mi < 4; ++mi)
#pragma unroll
            for (int ni = 0; ni < 4; ++ni)
                acc[4 + mi][ni] = __builtin_amdgcn_mfma_f32_16x16x32_bf16(
                    aP3[mi], bF1[ni], acc[4 + mi][ni], 0, 0, 0);
        __builtin_amdgcn_s_setprio(0);
        // boundary: loads for T+1 were issued 3-4 phases ago -> near-free wait;
        // the following barrier makes the cross-wave staging guarantee sound.
        asm volatile("s_waitcnt vmcnt(0)" ::: "memory");
        __builtin_amdgcn_s_barrier();
    }

    // ---- epilogue: 4 acc regs per frag = 4 parities of one oc -> 2x2 quad ----
    const float s2 = 1.41421356237309515f;
#pragma unroll
    for (int mi = 0; mi < 8; ++mi) {
        int oc = mt * 64 + wr * 32 + mi * 4 + q;
        float bv = bias[oc];
#pragma unroll
        for (int ni = 0; ni < 4; ++ni) {
            int n = nt * 256 + wc * 64 + ni * 16 + lr;
            int b = n >> 10, u = (n >> 5) & 31, v = n & 31;
            float y0 = acc[mi][ni][0] + bv;
            float y1 = acc[mi][ni][1] + bv;
            float y2 = acc[mi][ni][2] + bv;
            float y3 = acc[mi][ni][3] + bv;
            y0 = (y0 >= 0.f ? y0 : 0.2f * y0) * s2;
            y1 = (y1 >= 0.f ? y1 : 0.2f * y1) * s2;
            y2 = (y2 >= 0.f ? y2 : 0.2f * y2) * s2;
            y3 = (y3 >= 0.f ? y3 : 0.2f * y3) * s2;
            size_t base = (((size_t)b * OC + oc) * OHW + 2 * u) * OHW + 2 * v;
            *(f32x2*)(out + base)       = (f32x2){y0, y1};   // row 2u:   p=(0,0),(0,1)
            *(f32x2*)(out + base + OHW) = (f32x2){y2, y3};   // row 2u+1: p=(1,0),(1,1)
        }
    }
}

// ---------------------------------------------------------------------------
extern "C" void kernel_launch(void* const* d_in, const int* in_sizes, int n_in,
                              void* d_out, int out_size, void* d_ws, size_t ws_size,
                              hipStream_t stream) {
    const float* x    = (const float*)d_in[0];
    const float* w    = (const float*)d_in[1];
    const float* bias = (const float*)d_in[2];
    float* out = (float*)d_out;

    __hip_bfloat16* xcl  = (__hip_bfloat16*)d_ws;
    __hip_bfloat16* Amat = (__hip_bfloat16*)((char*)d_ws + WS_AMAT_OFF);

    xprep<<<32 * 34, 256, 0, stream>>>(x, xcl);
    wtrans<<<(OC * IC) / 256, 256, 0, stream>>>(w, Amat);
    // grid: 4 M-tiles * 128 N-tiles = 512 blocks, 512 threads
    gemm_conv<<<512, 512, 0, stream>>>(Amat, xcl, bias, out);
}